// Round 1
// baseline (929.279 us; speedup 1.0000x reference)
//
#include <hip/hip_runtime.h>

#define N_D 32
constexpr float EPS = 1e-12f;

// ---- Kernel 1: L2-normalize node features. 8 lanes per node, float4 each. ----
__global__ void agnn_norm_kernel(const float* __restrict__ x,
                                 float* __restrict__ xn,
                                 int n_nodes) {
    int gid  = blockIdx.x * blockDim.x + threadIdx.x;
    int node = gid >> 3;      // 8 lanes per node
    int lane = gid & 7;
    if (node >= n_nodes) return;

    float4 v = reinterpret_cast<const float4*>(x + (size_t)node * N_D)[lane];
    float ss = v.x * v.x + v.y * v.y + v.z * v.z + v.w * v.w;
    // butterfly reduce over the 8-lane group (all lanes get the sum)
    ss += __shfl_xor(ss, 1, 8);
    ss += __shfl_xor(ss, 2, 8);
    ss += __shfl_xor(ss, 4, 8);

    float r = 1.0f / fmaxf(sqrtf(ss), EPS);
    float4 o;
    o.x = v.x * r; o.y = v.y * r; o.z = v.z * r; o.w = v.w * r;
    reinterpret_cast<float4*>(xn + (size_t)node * N_D)[lane] = o;
}

// ---- Kernel 2: per-edge a = exp(beta * dot(xn[dst], xn[src])); seg_sum[dst] += a ----
__global__ void agnn_edge_alpha_kernel(const float* __restrict__ xn,
                                       const int* __restrict__ src_idx,
                                       const int* __restrict__ dst_idx,
                                       const float* __restrict__ beta,
                                       float* __restrict__ a_buf,
                                       float* __restrict__ seg_sum,
                                       int n_edges) {
    int gid  = blockIdx.x * blockDim.x + threadIdx.x;
    int e    = gid >> 3;      // 8 lanes per edge
    int lane = gid & 7;
    if (e >= n_edges) return;

    int s = src_idx[e];
    int d = dst_idx[e];

    float4 vs = reinterpret_cast<const float4*>(xn + (size_t)s * N_D)[lane];
    float4 vd = reinterpret_cast<const float4*>(xn + (size_t)d * N_D)[lane];
    float dot = vs.x * vd.x + vs.y * vd.y + vs.z * vd.z + vs.w * vd.w;
    dot += __shfl_xor(dot, 1, 8);
    dot += __shfl_xor(dot, 2, 8);
    dot += __shfl_xor(dot, 4, 8);

    if (lane == 0) {
        // alpha in (-1,1) since beta in [0,1), cos in [-1,1]; exp is safe
        // without the segment-max shift (softmax is shift-invariant).
        float a = expf(beta[0] * dot);
        a_buf[e] = a;
        unsafeAtomicAdd(&seg_sum[d], a);
    }
}

// ---- Kernel 3: out[dst] += (a / seg_sum[dst]) * x[src] ----
__global__ void agnn_edge_aggr_kernel(const float* __restrict__ x,
                                      const int* __restrict__ src_idx,
                                      const int* __restrict__ dst_idx,
                                      const float* __restrict__ a_buf,
                                      const float* __restrict__ seg_sum,
                                      float* __restrict__ out,
                                      int n_edges) {
    int gid  = blockIdx.x * blockDim.x + threadIdx.x;
    int e    = gid >> 3;      // 8 lanes per edge
    int lane = gid & 7;
    if (e >= n_edges) return;

    int s = src_idx[e];
    int d = dst_idx[e];
    float coef = a_buf[e] / seg_sum[d];

    float4 v = reinterpret_cast<const float4*>(x + (size_t)s * N_D)[lane];
    float* o = out + (size_t)d * N_D + lane * 4;
    unsafeAtomicAdd(o + 0, coef * v.x);
    unsafeAtomicAdd(o + 1, coef * v.y);
    unsafeAtomicAdd(o + 2, coef * v.z);
    unsafeAtomicAdd(o + 3, coef * v.w);
}

extern "C" void kernel_launch(void* const* d_in, const int* in_sizes, int n_in,
                              void* d_out, int out_size, void* d_ws, size_t ws_size,
                              hipStream_t stream) {
    const float* x    = (const float*)d_in[0];
    const float* beta = (const float*)d_in[1];
    const int*   ei   = (const int*)d_in[2];

    int n_nodes = in_sizes[0] / N_D;
    int n_edges = in_sizes[2] / 2;
    const int* src_idx = ei;             // edge_index[0]
    const int* dst_idx = ei + n_edges;   // edge_index[1]

    float* out = (float*)d_out;

    // ws layout: xn [N*32] | a_buf [E] | seg_sum [N]
    float* xn      = (float*)d_ws;
    float* a_buf   = xn + (size_t)n_nodes * N_D;
    float* seg_sum = a_buf + (size_t)n_edges;

    hipMemsetAsync(out, 0, (size_t)out_size * sizeof(float), stream);
    hipMemsetAsync(seg_sum, 0, (size_t)n_nodes * sizeof(float), stream);

    const int tpb = 256;

    long long norm_threads = (long long)n_nodes * 8;
    agnn_norm_kernel<<<(int)((norm_threads + tpb - 1) / tpb), tpb, 0, stream>>>(
        x, xn, n_nodes);

    long long edge_threads = (long long)n_edges * 8;
    int edge_blocks = (int)((edge_threads + tpb - 1) / tpb);

    agnn_edge_alpha_kernel<<<edge_blocks, tpb, 0, stream>>>(
        xn, src_idx, dst_idx, beta, a_buf, seg_sum, n_edges);

    agnn_edge_aggr_kernel<<<edge_blocks, tpb, 0, stream>>>(
        x, src_idx, dst_idx, a_buf, seg_sum, out, n_edges);
}

// Round 2
// 262.564 us; speedup vs baseline: 3.5392x; 3.5392x over previous
//
#include <hip/hip_runtime.h>

#define N_D 32
constexpr float EPS = 1e-12f;

// ---------------------------------------------------------------------------
// K1: per-node reciprocal L2 norm. 8 lanes per node, float4 each.
// ---------------------------------------------------------------------------
__global__ void agnn_rnorm_kernel(const float* __restrict__ x,
                                  float* __restrict__ rnorm,
                                  int n_nodes) {
    int gid  = blockIdx.x * blockDim.x + threadIdx.x;
    int node = gid >> 3;
    int lane = gid & 7;
    if (node >= n_nodes) return;

    float4 v = reinterpret_cast<const float4*>(x + (size_t)node * N_D)[lane];
    float ss = v.x * v.x + v.y * v.y + v.z * v.z + v.w * v.w;
    ss += __shfl_xor(ss, 1, 8);
    ss += __shfl_xor(ss, 2, 8);
    ss += __shfl_xor(ss, 4, 8);
    if (lane == 0)
        rnorm[node] = 1.0f / fmaxf(sqrtf(ss), EPS);
}

// ---------------------------------------------------------------------------
// K2: histogram of destination degrees. counts[] must be pre-zeroed.
// ---------------------------------------------------------------------------
__global__ void agnn_hist_kernel(const int* __restrict__ dst_idx,
                                 int* __restrict__ counts,
                                 int n_edges) {
    int e = blockIdx.x * blockDim.x + threadIdx.x;
    if (e >= n_edges) return;
    atomicAdd(&counts[dst_idx[e]], 1);
}

// ---------------------------------------------------------------------------
// K3a/b/c: exclusive scan counts[n] -> ptr[n] (3-kernel hierarchical scan).
// n = 100k -> 391 blocks of 256; bsums scanned by one 512-thread block.
// ---------------------------------------------------------------------------
__global__ void scan_k1(const int* __restrict__ counts,
                        int* __restrict__ ptr,
                        int* __restrict__ bsums,
                        int n) {
    __shared__ int tmp[256];
    int t = threadIdx.x;
    int i = blockIdx.x * 256 + t;
    int v = (i < n) ? counts[i] : 0;
    tmp[t] = v;
    __syncthreads();
    for (int off = 1; off < 256; off <<= 1) {
        int add = (t >= off) ? tmp[t - off] : 0;
        __syncthreads();
        tmp[t] += add;
        __syncthreads();
    }
    if (i < n) ptr[i] = tmp[t] - v;          // exclusive
    if (t == 255) bsums[blockIdx.x] = tmp[255];
}

__global__ void scan_k2(int* __restrict__ bsums, int nb) {
    __shared__ int tmp[512];
    int t = threadIdx.x;
    int v = (t < nb) ? bsums[t] : 0;
    tmp[t] = v;
    __syncthreads();
    for (int off = 1; off < 512; off <<= 1) {
        int add = (t >= off) ? tmp[t - off] : 0;
        __syncthreads();
        tmp[t] += add;
        __syncthreads();
    }
    if (t < nb) bsums[t] = tmp[t] - v;       // exclusive over block sums
}

__global__ void scan_k3(int* __restrict__ ptr,
                        const int* __restrict__ bsums,
                        int n, int total) {
    int i = blockIdx.x * 256 + threadIdx.x;
    if (i < n) ptr[i] += bsums[blockIdx.x];
    if (i == 0) ptr[n] = total;              // sentinel: ptr[N] = E
}

// ---------------------------------------------------------------------------
// K4: fused per-edge attention + CSR scatter.
// 8 lanes per edge compute dot(x[dst], x[src]); lane 0 computes
// a = exp(beta * dot * rnorm[s] * rnorm[d]), claims a slot in dst's bucket
// via atomicSub on counts (which drains back to 0), and writes (src, a).
// ---------------------------------------------------------------------------
__global__ void agnn_build_kernel(const float* __restrict__ x,
                                  const int* __restrict__ src_idx,
                                  const int* __restrict__ dst_idx,
                                  const float* __restrict__ beta,
                                  const float* __restrict__ rnorm,
                                  const int* __restrict__ ptr,
                                  int* __restrict__ counts,
                                  int2* __restrict__ perm_sa,
                                  int n_edges) {
    int gid  = blockIdx.x * blockDim.x + threadIdx.x;
    int e    = gid >> 3;
    int lane = gid & 7;
    if (e >= n_edges) return;

    int s = src_idx[e];
    int d = dst_idx[e];

    float4 vs = reinterpret_cast<const float4*>(x + (size_t)s * N_D)[lane];
    float4 vd = reinterpret_cast<const float4*>(x + (size_t)d * N_D)[lane];
    float dot = vs.x * vd.x + vs.y * vd.y + vs.z * vd.z + vs.w * vd.w;
    dot += __shfl_xor(dot, 1, 8);
    dot += __shfl_xor(dot, 2, 8);
    dot += __shfl_xor(dot, 4, 8);

    if (lane == 0) {
        // cos = dot * rnorm[s] * rnorm[d]; |beta*cos| < 1 so exp is safe
        // without the segment-max shift (softmax is shift-invariant).
        float a = expf(beta[0] * dot * rnorm[s] * rnorm[d]);
        int pos = ptr[d] + atomicSub(&counts[d], 1) - 1;
        int2 sa;
        sa.x = s;
        sa.y = __float_as_int(a);
        perm_sa[pos] = sa;
    }
}

// ---------------------------------------------------------------------------
// K5: gather-aggregate. One 8-lane group per destination node; register
// accumulation; single 128B row write, zero atomics.
// ---------------------------------------------------------------------------
__global__ void agnn_aggr_kernel(const float* __restrict__ x,
                                 const int* __restrict__ ptr,
                                 const int2* __restrict__ perm_sa,
                                 float* __restrict__ out,
                                 int n_nodes) {
    int gid  = blockIdx.x * blockDim.x + threadIdx.x;
    int node = gid >> 3;
    int lane = gid & 7;
    if (node >= n_nodes) return;

    int start = ptr[node];
    int end   = ptr[node + 1];

    // denominator: lanes stripe over the bucket, butterfly-combine
    float denom = 0.0f;
    for (int i = start + lane; i < end; i += 8)
        denom += __int_as_float(perm_sa[i].y);
    denom += __shfl_xor(denom, 1, 8);
    denom += __shfl_xor(denom, 2, 8);
    denom += __shfl_xor(denom, 4, 8);

    float4 acc = make_float4(0.f, 0.f, 0.f, 0.f);
    if (end > start) {
        float inv = 1.0f / denom;
        for (int i = start; i < end; ++i) {
            int2 sa = perm_sa[i];              // broadcast within group
            float coef = __int_as_float(sa.y) * inv;
            float4 v = reinterpret_cast<const float4*>(
                x + (size_t)sa.x * N_D)[lane];
            acc.x += coef * v.x;
            acc.y += coef * v.y;
            acc.z += coef * v.z;
            acc.w += coef * v.w;
        }
    }
    reinterpret_cast<float4*>(out + (size_t)node * N_D)[lane] = acc;
}

extern "C" void kernel_launch(void* const* d_in, const int* in_sizes, int n_in,
                              void* d_out, int out_size, void* d_ws, size_t ws_size,
                              hipStream_t stream) {
    const float* x    = (const float*)d_in[0];
    const float* beta = (const float*)d_in[1];
    const int*   ei   = (const int*)d_in[2];

    int n_nodes = in_sizes[0] / N_D;
    int n_edges = in_sizes[2] / 2;
    const int* src_idx = ei;
    const int* dst_idx = ei + n_edges;

    float* out = (float*)d_out;

    // ws layout (8B-aligned first): perm_sa[E] | rnorm[N] | ptr[N+1] |
    //                               counts[N] | bsums[512]
    char* w = (char*)d_ws;
    int2*  perm_sa = (int2*)w;                    w += (size_t)n_edges * sizeof(int2);
    float* rnorm   = (float*)w;                   w += (size_t)n_nodes * sizeof(float);
    int*   ptr     = (int*)w;                     w += (size_t)(n_nodes + 1) * sizeof(int);
    int*   counts  = (int*)w;                     w += (size_t)n_nodes * sizeof(int);

    hipMemsetAsync(counts, 0, (size_t)n_nodes * sizeof(int), stream);

    const int tpb = 256;
    int node_groups_blocks = (int)(((long long)n_nodes * 8 + tpb - 1) / tpb);
    int edge_blocks_1t     = (n_edges + tpb - 1) / tpb;
    int edge_blocks_8t     = (int)(((long long)n_edges * 8 + tpb - 1) / tpb);
    int scan_blocks        = (n_nodes + 255) / 256;   // 391 for N=100k (<=512)
    int* bsums             = (int*)w;                 // scan_blocks ints

    agnn_rnorm_kernel<<<node_groups_blocks, tpb, 0, stream>>>(x, rnorm, n_nodes);

    agnn_hist_kernel<<<edge_blocks_1t, tpb, 0, stream>>>(dst_idx, counts, n_edges);

    scan_k1<<<scan_blocks, 256, 0, stream>>>(counts, ptr, bsums, n_nodes);
    scan_k2<<<1, 512, 0, stream>>>(bsums, scan_blocks);
    scan_k3<<<scan_blocks, 256, 0, stream>>>(ptr, bsums, n_nodes, n_edges);

    agnn_build_kernel<<<edge_blocks_8t, tpb, 0, stream>>>(
        x, src_idx, dst_idx, beta, rnorm, ptr, counts, perm_sa, n_edges);

    agnn_aggr_kernel<<<node_groups_blocks, tpb, 0, stream>>>(
        x, ptr, perm_sa, out, n_nodes);
}